// Round 4
// baseline (852.858 us; speedup 1.0000x reference)
//
#include <hip/hip_runtime.h>

#define B_TOT 8192
#define T_OBS 128
#define T_FUT 64
#define T_ALL 192
#define DIN 5
#define HD 128
#define BT 32          // batch rows per block (two 16-row tiles)
#define LDSTR 136      // LDS row stride in shorts (272 B, 16B-aligned rows)

#define LOG2E 1.44269504088896340736f

typedef __attribute__((ext_vector_type(8))) short short8;
typedef __attribute__((ext_vector_type(4))) float f32x4;
typedef __attribute__((ext_vector_type(2))) unsigned int u32x2;
typedef __attribute__((ext_vector_type(4))) unsigned int u32x4;

__device__ inline short f2bf(float f) {
    unsigned u = __float_as_uint(f);
    u += 0x7FFFu + ((u >> 16) & 1u);   // round-to-nearest-even
    return (short)(u >> 16);
}

// packed f32->bf16 (RNE), lo <- s0, hi <- s1
__device__ inline unsigned cvtpk(float lo, float hi) {
    unsigned r;
    asm volatile("v_cvt_pk_bf16_f32 %0, %1, %2" : "=v"(r) : "v"(lo), "v"(hi));
    return r;
}

__device__ inline f32x4 MFMA(short8 a, short8 b, f32x4 c) {
    return __builtin_amdgcn_mfma_f32_16x16x32_bf16(a, b, c, 0, 0, 0);
}

__device__ inline short8 load_w8s(const float* p, float s) {
    float4 a = *reinterpret_cast<const float4*>(p);
    float4 b = *reinterpret_cast<const float4*>(p + 4);
    short8 r;
    r[0] = f2bf(a.x * s); r[1] = f2bf(a.y * s); r[2] = f2bf(a.z * s); r[3] = f2bf(a.w * s);
    r[4] = f2bf(b.x * s); r[5] = f2bf(b.y * s); r[6] = f2bf(b.z * s); r[7] = f2bf(b.w * s);
    return r;
}
__device__ inline short8 load_w5s(const float* p, float s) {
    short8 r = (short8)0;
    r[0] = f2bf(p[0] * s); r[1] = f2bf(p[1] * s); r[2] = f2bf(p[2] * s);
    r[3] = f2bf(p[3] * s); r[4] = f2bf(p[4] * s);
    return r;
}

// 512 threads = 8 waves, 256 blocks = 1 block/CU. R3 analysis: per step
// every wave re-read the FULL 32x128 h tile (8 KB x 8 waves = 64 KB through
// the 128 B/cyc LDS port = ~512+conflict cycles, ~22% of step time). This
// version splits waves over batch x gate-dims: wave w owns a-tile (w>>2)
// and h-dim slice (w&3)*32..+32 (all 3 gates). Same 30 MFMA/wave/step,
// same 8 h-elem/lane, but each wave reads only its own 4 KB A-tile ->
// LDS read traffic halves. Weights: 30 short8 = 120 VGPR/lane (total ~230,
// under the 256 cap for an 8-wave block; 1 block/CU is structural so
// occupancy is unaffected by VGPR use).
// Elementwise uses a combined denominator: h' = (h(1+ey) + ez(ey-1)) /
// ((1+ez)(1+ey)) -> 3 exp2 + 2 rcp per element (was 3+3).
__global__ __launch_bounds__(512, 1)
void gru_tracemodel_kernel(const float* __restrict__ obs, const float* __restrict__ target,
                           const float* __restrict__ eWih, const float* __restrict__ eWhh,
                           const float* __restrict__ ebih, const float* __restrict__ ebhh,
                           const float* __restrict__ cWih, const float* __restrict__ cWhh,
                           const float* __restrict__ cbih, const float* __restrict__ cbhh,
                           const float* __restrict__ headW, const float* __restrict__ headb,
                           float* __restrict__ out)
{
    __shared__ __attribute__((aligned(16))) short Abuf[2][BT][LDSTR];

    const int tid   = threadIdx.x;
    const int wave  = tid >> 6;    // 0..7
    const int lane  = tid & 63;
    const int q     = lane >> 4;   // k-group of A/B frags; row-group of C/D
    const int c     = lane & 15;   // non-K index of A/B frags; col of C/D
    const int b0    = blockIdx.x * BT;
    const int s4    = wave & 3;    // h-dim 32-slice
    const int a     = wave >> 2;   // batch half-tile (0 or 1)
    const int nbase = s4 * 32;     // within each gate's 128 dims

    // h0 = 0
    for (int i = tid; i < 2 * BT * LDSTR; i += 512) ((short*)Abuf)[i] = 0;

    // ---- weight fragments (A-operand: lane holds W'[n][k]) ----
    // [g] = 16-dim tile within the wave's 32-dim slice; kt 0..3 Whh, kt 4 Wih
    short8 Wr[2][5], Wz[2][5], Wn[2][5];
    f32x4  br4[2], bz4[2], bnh4[2], bni4[2];

    auto load_phase = [&](const float* Wih, const float* Whh,
                          const float* bih, const float* bhh) {
        #pragma unroll
        for (int g = 0; g < 2; ++g) {
            const int nr = 0 * HD + nbase + 16 * g + c;
            const int nz = 1 * HD + nbase + 16 * g + c;
            const int nn = 2 * HD + nbase + 16 * g + c;
            #pragma unroll
            for (int kt = 0; kt < 4; ++kt) {
                Wr[g][kt] = load_w8s(Whh + nr * HD + kt * 32 + q * 8, LOG2E);
                Wz[g][kt] = load_w8s(Whh + nz * HD + kt * 32 + q * 8, LOG2E);
                Wn[g][kt] = load_w8s(Whh + nn * HD + kt * 32 + q * 8, 2.f * LOG2E);
            }
            Wr[g][4] = (q == 0) ? load_w5s(Wih + nr * DIN, LOG2E) : (short8)0;
            Wz[g][4] = (q == 0) ? load_w5s(Wih + nz * DIN, LOG2E) : (short8)0;
            Wn[g][4] = (q == 0) ? load_w5s(Wih + nn * DIN, 2.f * LOG2E) : (short8)0;
            const int n0 = nbase + 16 * g + q * 4;
            #pragma unroll
            for (int r = 0; r < 4; ++r) {
                br4[g][r]  = (bih[0 * HD + n0 + r] + bhh[0 * HD + n0 + r]) * LOG2E;
                bz4[g][r]  = (bih[1 * HD + n0 + r] + bhh[1 * HD + n0 + r]) * LOG2E;
                bni4[g][r] = bih[2 * HD + n0 + r] * (2.f * LOG2E);
                bnh4[g][r] = bhh[2 * HD + n0 + r] * (2.f * LOG2E);
            }
        }
    };
    load_phase(eWih, eWhh, ebih, ebhh);

    // head fragments (all waves; active wave rotates). A: lane c holds
    // headW[d = c][k], d < 5.
    short8 Whd[4];
    f32x4  hb4;
    #pragma unroll
    for (int kt = 0; kt < 4; ++kt)
        Whd[kt] = (c < DIN) ? load_w8s(headW + c * HD + kt * 32 + q * 8, 1.f) : (short8)0;
    #pragma unroll
    for (int r = 0; r < 4; ++r)
        hb4[r] = (q * 4 + r < DIN) ? headb[q * 4 + r] : 0.f;

    // fp32 carried h: hreg[g][r] = h[batch a*16+c][dim nbase+16g+q*4+r]
    float hreg[2][4] = {{0.f,0.f,0.f,0.f},{0.f,0.f,0.f,0.f}};

    const float* obsr = obs    + (size_t)(b0 + a * 16 + c) * (T_OBS * DIN);
    const float* tgtr = target + (size_t)(b0 + a * 16 + c) * (T_FUT * DIN);
    float x5[5] = {0, 0, 0, 0, 0};
    if (q == 0) {
        #pragma unroll
        for (int j = 0; j < DIN; ++j) x5[j] = obsr[j];   // x_0
    }

    for (int t = 0; t <= T_ALL; ++t) {
        __syncthreads();
        const int p = t & 1;

        // h fragments (B-operand): lane holds h[batch a*16+c][k=kt*32+q*8..]
        short8 ah[4];
        const short* ap = &Abuf[p][a * 16 + c][0];
        #pragma unroll
        for (int kt = 0; kt < 4; ++kt)
            ah[kt] = *reinterpret_cast<const short8*>(ap + kt * 32 + q * 8);

        // fused head on previous step's h; two waves (one per a-tile),
        // rotating over the 4 slice-waves to balance skew
        if (t >= T_OBS + 1 && s4 == ((t - T_OBS - 1) & 3)) {
            const int s = t - (T_OBS + 1);
            const int d0 = q * 4;
            f32x4 acc = hb4;
            #pragma unroll
            for (int kt = 0; kt < 4; ++kt)
                acc = MFMA(Whd[kt], ah[kt], acc);
            // D[d = q*4+r][batch = a*16+c]
            if (d0 < DIN) {
                float* op = out + ((size_t)(b0 + a * 16 + c) * T_FUT + s) * DIN + d0;
                op[0] = acc[0];
                if (q == 0) { op[1] = acc[1]; op[2] = acc[2]; op[3] = acc[3]; }
            }
        }
        if (t == T_ALL) break;

        if (t == T_OBS) load_phase(cWih, cWhh, cbih, cbhh);  // switch to cell

        // x fragment (5th K-tile, B-operand): q==0 lanes hold x[batch][0..4]
        short8 ax;
        {
            unsigned u0 = 0, u1 = 0, u2 = 0;
            if (q == 0) {
                u0 = cvtpk(x5[0], x5[1]);
                u1 = cvtpk(x5[2], x5[3]);
                u2 = cvtpk(x5[4], 0.f);
            }
            u32x4 va = {u0, u1, u2, 0u};
            ax = __builtin_bit_cast(short8, va);
            const int tn = t + 1;   // prefetch next step's x
            if (q == 0 && tn < T_ALL) {
                const float* px = (tn < T_OBS)  ? (obsr + tn * DIN)
                                : (tn == T_OBS) ? (obsr + (T_OBS - 1) * DIN)
                                                : (tgtr + (tn - T_OBS - 1) * DIN);
                #pragma unroll
                for (int j = 0; j < DIN; ++j) x5[j] = px[j];
            }
        }

        // gate MFMAs (A = weights, B = h): 30/wave/step across g=0,1
        #pragma unroll
        for (int g = 0; g < 2; ++g) {
            f32x4 aR  = MFMA(Wr[g][0], ah[0], br4[g]);
            f32x4 aZ  = MFMA(Wz[g][0], ah[0], bz4[g]);
            f32x4 aNh = MFMA(Wn[g][0], ah[0], bnh4[g]);
            #pragma unroll
            for (int kt = 1; kt < 4; ++kt) {
                aR  = MFMA(Wr[g][kt], ah[kt], aR);
                aZ  = MFMA(Wz[g][kt], ah[kt], aZ);
                aNh = MFMA(Wn[g][kt], ah[kt], aNh);
            }
            aR  = MFMA(Wr[g][4], ax, aR);
            aZ  = MFMA(Wz[g][4], ax, aZ);
            f32x4 aNi = MFMA(Wn[g][4], ax, bni4[g]);

            // elementwise: accumulators pre-scaled by log2e (2log2e for n).
            // r = 1/(1+er); y = aNi + r*aNh; ey = exp2(y); ez = exp2(-aZ);
            // h' = (h*(1+ey) + ez*(ey-1)) / ((1+ez)*(1+ey))
            float hn[4];
            #pragma unroll
            for (int r = 0; r < 4; ++r) {
                float er  = __builtin_amdgcn_exp2f(-aR[r]);
                float rv  = __builtin_amdgcn_rcpf(1.f + er);
                float yv  = fmaf(rv, aNh[r], aNi[r]);
                float ey  = __builtin_amdgcn_exp2f(yv);
                float ez  = __builtin_amdgcn_exp2f(-aZ[r]);
                float d2  = 1.f + ey;
                float d1  = 1.f + ez;
                float em1 = ey - 1.f;
                float num = fmaf(ez, em1, hreg[g][r] * d2);
                float h_  = num * __builtin_amdgcn_rcpf(d1 * d2);
                hreg[g][r] = h_;
                hn[r] = h_;
            }
            // writeback: 4 consecutive h-dims of one row -> one b64 store
            u32x2 wv = { cvtpk(hn[0], hn[1]), cvtpk(hn[2], hn[3]) };
            *reinterpret_cast<u32x2*>(
                &Abuf[1 - p][a * 16 + c][nbase + 16 * g + q * 4]) = wv;
        }
    }
}

extern "C" void kernel_launch(void* const* d_in, const int* in_sizes, int n_in,
                              void* d_out, int out_size, void* d_ws, size_t ws_size,
                              hipStream_t stream)
{
    (void)in_sizes; (void)n_in; (void)d_ws; (void)ws_size; (void)out_size;
    gru_tracemodel_kernel<<<dim3(B_TOT / BT), dim3(512), 0, stream>>>(
        (const float*)d_in[0],  (const float*)d_in[1],
        (const float*)d_in[2],  (const float*)d_in[3],
        (const float*)d_in[4],  (const float*)d_in[5],
        (const float*)d_in[6],  (const float*)d_in[7],
        (const float*)d_in[8],  (const float*)d_in[9],
        (const float*)d_in[10], (const float*)d_in[11],
        (float*)d_out);
}